// Round 4
// baseline (73.023 us; speedup 1.0000x reference)
//
#include <hip/hip_runtime.h>
#include <hip/hip_bf16.h>

typedef __attribute__((ext_vector_type(8)))  short bf16x8;   // 8 bf16 = 4 VGPRs
typedef __attribute__((ext_vector_type(2)))  float f32x2;
typedef __attribute__((ext_vector_type(4)))  float f32x4;
typedef __attribute__((ext_vector_type(16))) float f32x16;

#define EMB_DIM 64
#define LDS_STRIDE 72   // shorts; 144 B row stride -> conflict-free b128 reads
#define LT_STRIDE 66    // floats; transposed writes land on 32 distinct banks

// Output is exactly symmetric: out[b,i,j] == out[b,j,i] bitwise (gram and x2
// terms symmetric in the reference too). Compute only tiles with tj >= ti
// (136 of 256 per batch); off-diagonal tiles mirror through LDS and store the
// transposed tile coalesced as well.
//
// Block = 64x64 output tile, 256 threads (4 waves).
// Phase 1: gather + Poincare-project 128 rows (64 i, 64 j) into LDS bf16;
//          per-row x2 = sum(bf16(e)^2) fp32 (deterministic everywhere ->
//          identical-token pairs cancel to ~ulp and hit the acosh clamp).
// Phase 2: per wave one 32x32 tile via 4x mfma_f32_32x32x16_bf16 (K=64),
//          fast-math acosh epilogue, coalesced stores (+ LDS-transposed
//          mirror store for off-diagonal tiles).
__global__ __launch_bounds__(256) void fused_bias_kernel(
    const int* __restrict__ ids, const float* __restrict__ weight,
    const float* __restrict__ scale_p, float* __restrict__ out,
    int S, int vocab)
{
    __shared__ short Es[128 * LDS_STRIDE];   // rows 0-63: i-rows, 64-127: j-rows
    __shared__ float x2s[128];
    float* Lt = (float*)Es;                  // reused after barrier: 64x66 fp32

    // ---- triangular tile decode: t -> (ti, tj), tj >= ti, NT=16 rows ----
    const int b = blockIdx.z;
    {
    }
    int tlin = blockIdx.x;
    int ti = (int)((33.0f - sqrtf(1089.0f - 8.0f * (float)tlin)) * 0.5f);
    // integer fixup (fp rounding safety): off(ti) = 16*ti - ti*(ti-1)/2
    while (16 * (ti + 1) - (ti + 1) * ti / 2 <= tlin) ++ti;
    while (16 * ti - ti * (ti - 1) / 2 > tlin) --ti;
    const int tj = ti + (tlin - (16 * ti - ti * (ti - 1) / 2));
    const int i0 = ti * 64;
    const int j0 = tj * 64;
    const bool diag = (ti == tj);

    const int t = threadIdx.x;

    // ---------------- Phase 1: gather + project ----------------
    {
        const int r  = t >> 1;                       // 0..127: LDS row
        const int h2 = t & 1;                        // half-row (32 dims)
        const int grow = (r < 64) ? (i0 + r) : (j0 + r - 64);
        int id = ids[(size_t)b * S + grow];
        id = min(max(id, 0), vocab - 1);

        const f32x4* W = (const f32x4*)(weight + (size_t)id * EMB_DIM + h2 * 32);
        f32x4 v[8];
        #pragma unroll
        for (int k = 0; k < 8; ++k) v[k] = W[k];     // 8 independent 16B loads

        float s = 0.f;
        #pragma unroll
        for (int k = 0; k < 8; ++k)
            s += v[k].x * v[k].x + v[k].y * v[k].y + v[k].z * v[k].z + v[k].w * v[k].w;
        s += __shfl_xor(s, 1);                       // full-row ||x||^2

        const float max_norm = 0.99999f;             // (1 - PROJ_EPS)/sqrt(C)
        float nrm = sqrtf(s);
        float mul = (nrm > max_norm) ? (max_norm / fmaxf(nrm, 1e-12f)) : 1.f;

        const float* vf = (const float*)v;
        bf16x8 hv[4];
        float s2 = 0.f;
        #pragma unroll
        for (int k = 0; k < 32; ++k) {
            __hip_bfloat16 hb = __float2bfloat16(vf[k] * mul);
            float hf = __bfloat162float(hb);
            s2 += hf * hf;
            hv[k >> 3][k & 7] = __builtin_bit_cast(short, hb);
        }
        s2 += __shfl_xor(s2, 1);                     // x2 of the rounded row

        short* dst = Es + r * LDS_STRIDE + h2 * 32;
        #pragma unroll
        for (int k = 0; k < 4; ++k)
            *(bf16x8*)(dst + k * 8) = hv[k];
        if (h2 == 0) x2s[r] = s2;
    }
    __syncthreads();

    // ---------------- Phase 2: MFMA ----------------
    const int wid  = t >> 6;
    const int lane = t & 63;
    const int m  = lane & 31;
    const int h  = lane >> 5;                        // k-half selector
    const int ia = (wid >> 1) * 32;                  // local i-row base
    const int jb = (wid & 1) * 32;                   // local j-row base

    const short* Ear = Es + (ia + m) * LDS_STRIDE + h * 8;
    const short* Ebr = Es + (64 + jb + m) * LDS_STRIDE + h * 8;

    f32x16 acc = {};
    #pragma unroll
    for (int kb = 0; kb < 4; ++kb) {
        bf16x8 av = *(const bf16x8*)(Ear + kb * 16);
        bf16x8 bv = *(const bf16x8*)(Ebr + kb * 16);
        acc = __builtin_amdgcn_mfma_f32_32x32x16_bf16(av, bv, acc, 0, 0, 0);
    }
    __syncthreads();   // all waves done reading Es before Lt overwrites it

    // ---------------- epilogue + primary store ----------------
    const float xj    = x2s[64 + jb + m];
    const float scale = scale_p[0];
    const float omxj  = 1.f - xj;

    float* O = out + ((size_t)b * S + i0 + ia + 4 * h) * S + j0 + jb + m;

    #pragma unroll
    for (int g = 0; g < 4; ++g) {
        f32x4 xi4 = *(const f32x4*)(x2s + ia + g * 8 + 4 * h);   // broadcast read
        #pragma unroll
        for (int e = 0; e < 4; ++e) {
            float gv = acc[g * 4 + e];
            float xi = xi4[e];
            float sq  = fmaxf(xi + xj - 2.f * gv, 0.f);          // ||xi - xj||^2
            float den = (1.f - xi) * omxj;
            // u = arg - 1, clamped to fp32(1 + 1e-7) - 1 (matches ref clamp)
            float u = fmaxf(2.f * sq * __builtin_amdgcn_rcpf(den), 1.1920929e-7f);
            // acosh(1+u) = ln(1 + u + sqrt(u*(u+2))); v_log_f32 is log2
            float w = 1.f + u + __builtin_amdgcn_sqrtf(u * (u + 2.f));
            float val = -scale * (0.69314718056f * __builtin_amdgcn_logf(w));
            O[(size_t)(g * 8 + e) * S] = val;
            if (!diag) {
                int li = ia + 4 * h + g * 8 + e;                 // local i
                int lj = jb + m;                                 // local j
                Lt[lj * LT_STRIDE + li] = val;                   // transposed stash
            }
        }
    }

    // ---------------- mirror store (off-diagonal only) ----------------
    if (!diag) {
        __syncthreads();
        const int row0 = t >> 5;            // 0..7
        const int c2   = (t & 31) * 2;      // even column
        #pragma unroll
        for (int r8 = 0; r8 < 8; ++r8) {
            int row = row0 + r8 * 8;
            f32x2 v2 = *(const f32x2*)(Lt + row * LT_STRIDE + c2);
            *(f32x2*)(out + ((size_t)b * S + j0 + row) * S + i0 + c2) = v2;
        }
    }
}

extern "C" void kernel_launch(void* const* d_in, const int* in_sizes, int n_in,
                              void* d_out, int out_size, void* d_ws, size_t ws_size,
                              hipStream_t stream) {
    const int*   ids     = (const int*)d_in[0];
    const float* weight  = (const float*)d_in[1];
    const float* scale_p = (const float*)d_in[2];
    float*       out     = (float*)d_out;

    const int n_tok = in_sizes[0];              // batch * seq = 4096
    const int vocab = in_sizes[1] / EMB_DIM;    // 30522
    const int S     = out_size / n_tok;         // 1024
    const int B     = n_tok / S;                // 4

    const int NT = S / 64;                      // 16 tile-rows
    dim3 grid(NT * (NT + 1) / 2, 1, B);         // 136 upper-tri tiles per batch
    fused_bias_kernel<<<grid, 256, 0, stream>>>(ids, weight, scale_p, out, S, vocab);
}

// Round 5
// 72.949 us; speedup vs baseline: 1.0010x; 1.0010x over previous
//
#include <hip/hip_runtime.h>
#include <hip/hip_bf16.h>

typedef __attribute__((ext_vector_type(8)))  short bf16x8;   // 8 bf16 = 4 VGPRs
typedef __attribute__((ext_vector_type(4)))  float f32x4;
typedef __attribute__((ext_vector_type(16))) float f32x16;

#define EMB_DIM 64
#define LDS_STRIDE 72   // 64 + 8 pad shorts -> 144 B row stride: b128 reads at
                        // 32-row stride start at bank 4*m%32 -> even spread

// One fused kernel. Block = 64x64 output tile, 256 threads (4 waves).
// Phase 1: gather + Poincare-project the block's 128 rows (64 i, 64 j) into
//          LDS as bf16; per-row x2 = sum(bf16(e)^2) in fp32 (deterministic
//          across blocks -> identical-token pairs cancel to ~ulp and hit the
//          acosh clamp, same as the reference).
// Phase 2: each wave: one 32x32 tile via 4x mfma_f32_32x32x16_bf16 (K=64),
//          fast-math acosh epilogue, coalesced stores.
// NOTE (round-4 experiment): exploiting output symmetry (half the blocks +
// LDS-mirrored stores) was NEUTRAL -> kernel is store/launch-bound, not
// compute-bound. Keep the simpler full-tile version (best measured).
__global__ __launch_bounds__(256) void fused_bias_kernel(
    const int* __restrict__ ids, const float* __restrict__ weight,
    const float* __restrict__ scale_p, float* __restrict__ out,
    int S, int vocab)
{
    __shared__ short Es[128 * LDS_STRIDE];   // rows 0-63: i-rows, 64-127: j-rows
    __shared__ float x2s[128];

    const int b  = blockIdx.z;
    const int i0 = blockIdx.y * 64;
    const int j0 = blockIdx.x * 64;
    const int t  = threadIdx.x;

    // ---------------- Phase 1: gather + project ----------------
    {
        const int r  = t >> 1;                       // 0..127: LDS row
        const int h2 = t & 1;                        // half-row (32 dims)
        const int grow = (r < 64) ? (i0 + r) : (j0 + r - 64);
        int id = ids[(size_t)b * S + grow];
        id = min(max(id, 0), vocab - 1);

        const f32x4* W = (const f32x4*)(weight + (size_t)id * EMB_DIM + h2 * 32);
        f32x4 v[8];
        #pragma unroll
        for (int k = 0; k < 8; ++k) v[k] = W[k];     // 8 independent 16B loads

        float s = 0.f;
        #pragma unroll
        for (int k = 0; k < 8; ++k)
            s += v[k].x * v[k].x + v[k].y * v[k].y + v[k].z * v[k].z + v[k].w * v[k].w;
        s += __shfl_xor(s, 1);                       // full-row ||x||^2

        const float max_norm = 0.99999f;             // (1 - PROJ_EPS)/sqrt(C)
        float nrm = sqrtf(s);
        float mul = (nrm > max_norm) ? (max_norm / fmaxf(nrm, 1e-12f)) : 1.f;

        const float* vf = (const float*)v;
        bf16x8 hv[4];
        float s2 = 0.f;
        #pragma unroll
        for (int k = 0; k < 32; ++k) {
            __hip_bfloat16 hb = __float2bfloat16(vf[k] * mul);
            float hf = __bfloat162float(hb);
            s2 += hf * hf;
            hv[k >> 3][k & 7] = __builtin_bit_cast(short, hb);
        }
        s2 += __shfl_xor(s2, 1);                     // x2 of the rounded row

        short* dst = Es + r * LDS_STRIDE + h2 * 32;
        #pragma unroll
        for (int k = 0; k < 4; ++k)
            *(bf16x8*)(dst + k * 8) = hv[k];
        if (h2 == 0) x2s[r] = s2;
    }
    __syncthreads();

    // ---------------- Phase 2: MFMA + epilogue ----------------
    const int wid  = t >> 6;
    const int lane = t & 63;
    const int m  = lane & 31;
    const int h  = lane >> 5;                        // k-half selector
    const int ia = (wid >> 1) * 32;                  // local i-row base
    const int jb = (wid & 1) * 32;                   // local j-row base

    const short* Ear = Es + (ia + m) * LDS_STRIDE + h * 8;
    const short* Ebr = Es + (64 + jb + m) * LDS_STRIDE + h * 8;

    f32x16 acc = {};
    #pragma unroll
    for (int kb = 0; kb < 4; ++kb) {
        bf16x8 av = *(const bf16x8*)(Ear + kb * 16);
        bf16x8 bv = *(const bf16x8*)(Ebr + kb * 16);
        acc = __builtin_amdgcn_mfma_f32_32x32x16_bf16(av, bv, acc, 0, 0, 0);
    }

    const float xj    = x2s[64 + jb + m];
    const float scale = scale_p[0];
    const float omxj  = 1.f - xj;

    float* O = out + ((size_t)b * S + i0 + ia + 4 * h) * S + j0 + jb + m;

    #pragma unroll
    for (int g = 0; g < 4; ++g) {
        f32x4 xi4 = *(const f32x4*)(x2s + ia + g * 8 + 4 * h);   // broadcast read
        #pragma unroll
        for (int e = 0; e < 4; ++e) {
            float gv = acc[g * 4 + e];
            float xi = xi4[e];
            float sq  = fmaxf(xi + xj - 2.f * gv, 0.f);          // ||xi - xj||^2
            float den = (1.f - xi) * omxj;
            // u = arg - 1, clamped to fp32(1 + 1e-7) - 1 (matches ref clamp)
            float u = fmaxf(2.f * sq * __builtin_amdgcn_rcpf(den), 1.1920929e-7f);
            // acosh(1+u) = ln(1 + u + sqrt(u*(u+2))); v_log_f32 is log2
            float w = 1.f + u + __builtin_amdgcn_sqrtf(u * (u + 2.f));
            float dist = 0.69314718056f * __builtin_amdgcn_logf(w);
            O[(size_t)(g * 8 + e) * S] = -scale * dist;          // scale * -dist
        }
    }
}

extern "C" void kernel_launch(void* const* d_in, const int* in_sizes, int n_in,
                              void* d_out, int out_size, void* d_ws, size_t ws_size,
                              hipStream_t stream) {
    const int*   ids     = (const int*)d_in[0];
    const float* weight  = (const float*)d_in[1];
    const float* scale_p = (const float*)d_in[2];
    float*       out     = (float*)d_out;

    const int n_tok = in_sizes[0];              // batch * seq = 4096
    const int vocab = in_sizes[1] / EMB_DIM;    // 30522
    const int S     = out_size / n_tok;         // 1024
    const int B     = n_tok / S;                // 4

    dim3 grid(S / 64, S / 64, B);
    fused_bias_kernel<<<grid, 256, 0, stream>>>(ids, weight, scale_p, out, S, vocab);
}